// Round 1
// baseline (1533.331 us; speedup 1.0000x reference)
//
#include <hip/hip_runtime.h>
#include <math.h>

#define BB 128
#define SS 80
#define HH 512
#define TT 27      // T-1
#define TFULL 28
#define VV 8000
#define WDIM 1024
#define G4 2048

// ---------------- workspace layout (floats) ----------------
// vA:512 | vB:512 | u:512 | part:32*512 | ctx:128*512 | gb:128*2048 |
// xg:3456*2048 | hs:3456*512 | h0:65536 | h1:65536 | c:65536
#define OFF_VA   0
#define OFF_VB   512
#define OFF_U    1024
#define OFF_PART 1536
#define OFF_CTX  17920
#define OFF_GB   83456
#define OFF_XG   345600
#define OFF_HS   7423488
#define OFF_H0   9192960
#define OFF_H1   9258496
#define OFF_C    9324032
// total 9389568 floats = ~35.8 MiB

// v_out[k] = sum_o W[o*ldw + koff + k] * vin[o], two-stage deterministic
__global__ __launch_bounds__(512) void matvec_col_partial(
    const float* __restrict__ W, int ldw, int koff,
    const float* __restrict__ vin, float* __restrict__ part)
{
    int k = threadIdx.x;           // 0..511
    int o0 = blockIdx.x * 16;      // 32 blocks
    float acc = 0.f;
    #pragma unroll
    for (int o = 0; o < 16; ++o)
        acc += W[(size_t)(o0 + o) * ldw + koff + k] * vin[o0 + o];
    part[blockIdx.x * 512 + k] = acc;
}

__global__ __launch_bounds__(512) void matvec_combine(
    const float* __restrict__ part, float* __restrict__ vout)
{
    int k = threadIdx.x;
    float s = 0.f;
    #pragma unroll
    for (int c = 0; c < 32; ++c) s += part[c * 512 + k];
    vout[k] = s;
}

// scores[b,s] = enc[b,s,:]·u ; softmax over s ; ctx[b,:] = wts @ enc[b]
__global__ __launch_bounds__(256) void attn_ctx(
    const float* __restrict__ enc, const float* __restrict__ u,
    float* __restrict__ ctx)
{
    __shared__ float su[HH];
    __shared__ float sw[SS];
    __shared__ float ssum;
    int b = blockIdx.x, tid = threadIdx.x;
    su[tid] = u[tid];
    su[tid + 256] = u[tid + 256];
    __syncthreads();
    const float* eb = enc + (size_t)b * SS * HH;
    int wave = tid >> 6, lane = tid & 63;
    for (int s = wave; s < SS; s += 4) {
        const float* row = eb + s * HH;
        float acc = 0.f;
        for (int k = lane; k < HH; k += 64) acc += row[k] * su[k];
        #pragma unroll
        for (int off = 32; off; off >>= 1) acc += __shfl_down(acc, off);
        if (lane == 0) sw[s] = acc;
    }
    __syncthreads();
    if (tid == 0) {
        float mx = sw[0];
        for (int s = 1; s < SS; ++s) mx = fmaxf(mx, sw[s]);
        float sum = 0.f;
        for (int s = 0; s < SS; ++s) { float e = expf(sw[s] - mx); sw[s] = e; sum += e; }
        ssum = sum;
    }
    __syncthreads();
    float inv = 1.0f / ssum;
    for (int k = tid; k < HH; k += 256) {
        float acc = 0.f;
        #pragma unroll 4
        for (int s = 0; s < SS; ++s) acc += sw[s] * eb[s * HH + k];
        ctx[(size_t)b * HH + k] = acc * inv;
    }
}

// C = A @ Bm^T (+bias1+bias2). A: MxK row-major (optional gather for xg rows),
// Bm: NxK row-major with row stride ldb and column offset kob.
// outMode 0: C[m*N+n]   outMode 1 (logits): C[((m&127)*27 + m>>7)*8000 + n]
__global__ __launch_bounds__(256) void gemm_nt(
    int M, int N, int K,
    const float* __restrict__ A, int lda, const int* __restrict__ gidx,
    const float* __restrict__ Bm, int ldb, int kob,
    const float* __restrict__ bias1, const float* __restrict__ bias2,
    float* __restrict__ C, int outMode)
{
    __shared__ float As[16][132];
    __shared__ float Bs[16][132];
    int tid = threadIdx.x;
    int m0 = blockIdx.y * 128, n0 = blockIdx.x * 128;
    int tn = tid & 15, tm = tid >> 4;
    float acc[8][8];
    #pragma unroll
    for (int i = 0; i < 8; ++i)
        #pragma unroll
        for (int j = 0; j < 8; ++j) acc[i][j] = 0.f;

    int lr = tid >> 2;          // 0..63
    int lk = (tid & 3) * 4;     // 0,4,8,12

    for (int k0 = 0; k0 < K; k0 += 16) {
        #pragma unroll
        for (int half = 0; half < 2; ++half) {
            int mr = lr + half * 64;
            int m = m0 + mr;
            float4 va = make_float4(0.f, 0.f, 0.f, 0.f);
            if (m < M) {
                const float* arow;
                if (gidx) {
                    int tt = m >> 7, bb = m & 127;
                    arow = A + (size_t)gidx[bb * TFULL + tt] * lda;
                } else {
                    arow = A + (size_t)m * lda;
                }
                va = *(const float4*)(arow + k0 + lk);
            }
            As[lk + 0][mr] = va.x; As[lk + 1][mr] = va.y;
            As[lk + 2][mr] = va.z; As[lk + 3][mr] = va.w;

            int n = n0 + mr;
            float4 vb = make_float4(0.f, 0.f, 0.f, 0.f);
            if (n < N) vb = *(const float4*)(Bm + (size_t)n * ldb + kob + k0 + lk);
            Bs[lk + 0][mr] = vb.x; Bs[lk + 1][mr] = vb.y;
            Bs[lk + 2][mr] = vb.z; Bs[lk + 3][mr] = vb.w;
        }
        __syncthreads();
        #pragma unroll
        for (int kk = 0; kk < 16; ++kk) {
            float4 a0 = *(const float4*)&As[kk][tm * 8];
            float4 a1 = *(const float4*)&As[kk][tm * 8 + 4];
            float4 b0 = *(const float4*)&Bs[kk][tn * 8];
            float4 b1 = *(const float4*)&Bs[kk][tn * 8 + 4];
            float av[8] = {a0.x, a0.y, a0.z, a0.w, a1.x, a1.y, a1.z, a1.w};
            float bv[8] = {b0.x, b0.y, b0.z, b0.w, b1.x, b1.y, b1.z, b1.w};
            #pragma unroll
            for (int i = 0; i < 8; ++i)
                #pragma unroll
                for (int j = 0; j < 8; ++j)
                    acc[i][j] += av[i] * bv[j];
        }
        __syncthreads();
    }
    #pragma unroll
    for (int i = 0; i < 8; ++i) {
        int m = m0 + tm * 8 + i;
        if (m >= M) continue;
        #pragma unroll
        for (int j = 0; j < 8; ++j) {
            int n = n0 + tn * 8 + j;
            if (n >= N) continue;
            float v = acc[i][j];
            if (bias1) v += bias1[n];
            if (bias2) v += bias2[n];
            size_t oi;
            if (outMode == 0) oi = (size_t)m * N + n;
            else { int bb = m & 127, tt = m >> 7; oi = ((size_t)bb * TT + tt) * (size_t)VV + n; }
            C[oi] = v;
        }
    }
}

__global__ __launch_bounds__(256) void init_hc(
    const float* __restrict__ ehs, float* __restrict__ h0, float* __restrict__ c)
{
    int i = blockIdx.x * 256 + threadIdx.x;  // 65536 total
    h0[i] = ehs[i];
    c[i] = 0.f;
}

// one LSTM step: gates = h@w_hh^T + xg[t] + gbase ; elementwise update
// grid (16 k-tiles, 16 b-tiles), block 256: each thread = one (b,k), 4 gates
__global__ __launch_bounds__(256) void lstm_step(
    int t, const float* __restrict__ hin, float* __restrict__ hout,
    float* __restrict__ cb, const float* __restrict__ whh,
    const float* __restrict__ xg, const float* __restrict__ gb,
    float* __restrict__ hs)
{
    __shared__ float swt[128][36];
    __shared__ float sh[8][32];
    int tid = threadIdx.x;
    int k0 = blockIdx.x * 32, b0 = blockIdx.y * 8;
    int tk = tid & 31, tb = tid >> 5;
    float acc[4] = {0.f, 0.f, 0.f, 0.f};
    int lr = tid >> 1;            // 0..127  (gate*32 + kloc)
    int lkc = (tid & 1) * 16;     // 0 or 16

    for (int kk0 = 0; kk0 < 512; kk0 += 32) {
        {
            int g = lr >> 5, kloc = lr & 31;
            const float* wr = whh + (size_t)(g * 512 + k0 + kloc) * 512 + kk0 + lkc;
            float4 v0 = *(const float4*)(wr + 0);
            float4 v1 = *(const float4*)(wr + 4);
            float4 v2 = *(const float4*)(wr + 8);
            float4 v3 = *(const float4*)(wr + 12);
            *(float4*)&swt[lr][lkc + 0]  = v0;
            *(float4*)&swt[lr][lkc + 4]  = v1;
            *(float4*)&swt[lr][lkc + 8]  = v2;
            *(float4*)&swt[lr][lkc + 12] = v3;
        }
        {
            int r = tid >> 5, kk = tid & 31;
            sh[r][kk] = hin[(size_t)(b0 + r) * 512 + kk0 + kk];
        }
        __syncthreads();
        #pragma unroll
        for (int q = 0; q < 8; ++q) {
            float4 hv = *(const float4*)&sh[tb][q * 4];
            #pragma unroll
            for (int g = 0; g < 4; ++g) {
                float4 wv = *(const float4*)&swt[g * 32 + tk][q * 4];
                acc[g] += hv.x * wv.x + hv.y * wv.y + hv.z * wv.z + hv.w * wv.w;
            }
        }
        __syncthreads();
    }

    int b = b0 + tb, k = k0 + tk;
    size_t m = (size_t)t * 128 + b;
    size_t xb = m * 2048;
    size_t gbb = (size_t)b * 2048;
    float gi = acc[0] + xg[xb + k]        + gb[gbb + k];
    float gf = acc[1] + xg[xb + 512 + k]  + gb[gbb + 512 + k];
    float gg = acc[2] + xg[xb + 1024 + k] + gb[gbb + 1024 + k];
    float go = acc[3] + xg[xb + 1536 + k] + gb[gbb + 1536 + k];
    float si = 1.f / (1.f + expf(-gi));
    float sf = 1.f / (1.f + expf(-gf));
    float so = 1.f / (1.f + expf(-go));
    float tg = tanhf(gg);
    float cold = cb[(size_t)b * 512 + k];
    float cn = sf * cold + si * tg;
    float hn = so * tanhf(cn);
    cb[(size_t)b * 512 + k] = cn;
    hout[(size_t)b * 512 + k] = hn;
    hs[m * 512 + k] = hn;
}

// one wave per output row r = b*27+t, ties -> first index (np.argmax)
__global__ __launch_bounds__(256) void argmax_k(
    const float* __restrict__ logits, float* __restrict__ preds)
{
    int r = blockIdx.x * 4 + (threadIdx.x >> 6);
    int lane = threadIdx.x & 63;
    const float* row = logits + (size_t)r * VV;
    float best = -INFINITY;
    int bi = 0;
    for (int v = lane; v < VV; v += 64) {
        float x = row[v];
        if (x > best) { best = x; bi = v; }
    }
    #pragma unroll
    for (int off = 32; off; off >>= 1) {
        float ob = __shfl_down(best, off);
        int oi = __shfl_down(bi, off);
        if (ob > best || (ob == best && oi < bi)) { best = ob; bi = oi; }
    }
    if (lane == 0) preds[r] = (float)bi;
}

extern "C" void kernel_launch(void* const* d_in, const int* in_sizes, int n_in,
                              void* d_out, int out_size, void* d_ws, size_t ws_size,
                              hipStream_t stream) {
    const float* ehs   = (const float*)d_in[0];
    const float* enc   = (const float*)d_in[1];
    const int*   tgt   = (const int*)d_in[2];
    const float* emb   = (const float*)d_in[4];
    const float* fc1w  = (const float*)d_in[5];
    const float* fc2w  = (const float*)d_in[7];
    const float* fc3w  = (const float*)d_in[9];
    const float* fc4w  = (const float*)d_in[11];
    const float* attnw = (const float*)d_in[13];
    const float* wih   = (const float*)d_in[14];
    const float* whh   = (const float*)d_in[15];
    const float* bih   = (const float*)d_in[16];
    const float* bhh   = (const float*)d_in[17];
    const float* outw  = (const float*)d_in[18];
    const float* outb  = (const float*)d_in[19];
    float* out = (float*)d_out;
    float* ws  = (float*)d_ws;

    float* vA   = ws + OFF_VA;
    float* vB   = ws + OFF_VB;
    float* u    = ws + OFF_U;
    float* part = ws + OFF_PART;
    float* ctx  = ws + OFF_CTX;
    float* gb   = ws + OFF_GB;
    float* xg   = ws + OFF_XG;
    float* hs   = ws + OFF_HS;
    float* h0b  = ws + OFF_H0;
    float* h1b  = ws + OFF_H1;
    float* cb   = ws + OFF_C;

    // u = W1e^T W2^T W3^T W4^T attn_w  (softmax shift-invariance kills h & bias terms)
    matvec_col_partial<<<32, 512, 0, stream>>>(fc4w, 512, 0, attnw, part);
    matvec_combine<<<1, 512, 0, stream>>>(part, vA);
    matvec_col_partial<<<32, 512, 0, stream>>>(fc3w, 512, 0, vA, part);
    matvec_combine<<<1, 512, 0, stream>>>(part, vB);
    matvec_col_partial<<<32, 512, 0, stream>>>(fc2w, 512, 0, vB, part);
    matvec_combine<<<1, 512, 0, stream>>>(part, vA);
    matvec_col_partial<<<32, 512, 0, stream>>>(fc1w, 1024, 0, vA, part);
    matvec_combine<<<1, 512, 0, stream>>>(part, u);

    attn_ctx<<<128, 256, 0, stream>>>(enc, u, ctx);

    // gbase = ctx @ Wc^T + b_ih + b_hh   (Wc = w_ih[:,1024:])
    {
        dim3 g(16, 1);
        gemm_nt<<<g, 256, 0, stream>>>(128, 2048, 512, ctx, 512, nullptr,
                                       wih, 1536, 1024, bih, bhh, gb, 0);
    }
    // xg[t,b,:] = emb[tgt[b,t]] @ Wx^T   (Wx = w_ih[:,:1024])
    {
        dim3 g(16, TT);
        gemm_nt<<<g, 256, 0, stream>>>(TT * 128, 2048, 1024, emb, 1024, tgt,
                                       wih, 1536, 0, nullptr, nullptr, xg, 0);
    }

    init_hc<<<256, 256, 0, stream>>>(ehs, h0b, cb);

    for (int t = 0; t < TT; ++t) {
        const float* hin = (t & 1) ? h1b : h0b;
        float* hout      = (t & 1) ? h0b : h1b;
        dim3 g(16, 16);
        lstm_step<<<g, 256, 0, stream>>>(t, hin, hout, cb, whh, xg, gb, hs);
    }

    // logits = Hs @ out_w^T + out_b, scattered to (b, t, v) layout
    {
        dim3 g(63, TT);
        gemm_nt<<<g, 256, 0, stream>>>(TT * 128, VV, 512, hs, 512, nullptr,
                                       outw, 512, 0, outb, nullptr, out, 1);
    }

    argmax_k<<<864, 256, 0, stream>>>(out, out + (size_t)TT * 128 * VV);
}

// Round 2
// 947.200 us; speedup vs baseline: 1.6188x; 1.6188x over previous
//
#include <hip/hip_runtime.h>
#include <math.h>

#define BB 128
#define SS 80
#define HH 512
#define TT 27      // T-1
#define TFULL 28
#define VV 8000
#define WDIM 1024
#define G4 2048

typedef __attribute__((ext_vector_type(4))) float f32x4;
typedef __attribute__((ext_vector_type(8))) short bfrag;

// ---------------- fp32 workspace layout (floats) ----------------
#define OFF_VA   0
#define OFF_VB   512
#define OFF_U    1024
#define OFF_PART 1536
#define OFF_CTX  17920
#define OFF_GB   83456
#define OFF_XG   345600          // 3456*2048
#define OFF_C    7423488         // 128*512
#define FP32_WS_FLOATS 7489536
// ---------------- bf16 workspace (ushort offsets from bf16 base) ----------------
#define O_H3     0               // 28*128 rows x 1536  (row t*128+b; rows 0..127 = h0)
#define O_WHH3   5505024         // 2048 x 1536 (gate-interleaved rows)
#define O_R      8650752
#define O_A3X    O_R             // 3456 x 3072
#define O_B3X    (O_R + 10616832)// 2048 x 3072
#define O_B3L    O_R             // 8000 x 1536 (overlays A3X/B3X after xg gemm)

__device__ __forceinline__ unsigned short f2bf(float x) {
    unsigned int u = __float_as_uint(x);
    unsigned int r = (u + 0x7fff + ((u >> 16) & 1)) >> 16;
    return (unsigned short)r;
}
__device__ __forceinline__ float bf2f(unsigned short h) {
    return __uint_as_float(((unsigned int)h) << 16);
}
__device__ __forceinline__ void gload16(void* lds, const void* g) {
    __builtin_amdgcn_global_load_lds(
        (__attribute__((address_space(1))) void*)g,
        (__attribute__((address_space(3))) void*)lds, 16, 0, 0);
}

// ---------- split-bf16 conversion ----------
// dst row r (3K wide): A-side: [hi | hi | lo]  B-side: [hi | lo | hi]
// mode 0: src row = r ; mode 1: gather emb row = gidx[(r&127)*28 + (r>>7)] ;
// mode 2: lstm gate-interleave: src row = ((r>>4)&3)*512 + (r>>6)*16 + (r&15)
__global__ __launch_bounds__(256) void conv_split(
    const float* __restrict__ src, int ld, int koff, int K,
    int mode, int bside, const int* __restrict__ gidx,
    unsigned short* __restrict__ dst)
{
    int r = blockIdx.x;
    int sr = r;
    if (mode == 1) { int b = r & 127, t = r >> 7; sr = gidx[b * TFULL + t]; }
    else if (mode == 2) { sr = ((r >> 4) & 3) * 512 + (r >> 6) * 16 + (r & 15); }
    const float* s = src + (size_t)sr * ld + koff;
    unsigned short* d = dst + (size_t)r * (3 * K);
    int off_mid = bside ? 2 * K : K;   // where the duplicated hi goes
    int off_lo  = bside ? K : 2 * K;
    for (int c = threadIdx.x * 4; c < K; c += 1024) {
        float4 v = *(const float4*)(s + c);
        ushort4 hi, lo;
        hi.x = f2bf(v.x); lo.x = f2bf(v.x - bf2f(hi.x));
        hi.y = f2bf(v.y); lo.y = f2bf(v.y - bf2f(hi.y));
        hi.z = f2bf(v.z); lo.z = f2bf(v.z - bf2f(hi.z));
        hi.w = f2bf(v.w); lo.w = f2bf(v.w - bf2f(hi.w));
        *(ushort4*)(d + c) = hi;
        *(ushort4*)(d + off_mid + c) = hi;
        *(ushort4*)(d + off_lo + c) = lo;
    }
}

// ---------- bf16 MFMA GEMM: C = A3 @ B3^T (+bias), 128x128 tile, BK=64 ----------
// A3: M x K3 bf16 row-major; B3: N x K3 bf16 row-major.
// outMode 0: C[m*N+n]   outMode 1: C[((m&127)*27 + (m>>7))*8000 + n]
__global__ __launch_bounds__(256) void gemm_bf16_nt(
    int M, int N, int K3,
    const unsigned short* __restrict__ A3,
    const unsigned short* __restrict__ B3,
    const float* __restrict__ bias,
    float* __restrict__ C, int outMode)
{
    __shared__ unsigned short Asm[128 * 64];
    __shared__ unsigned short Bsm[128 * 64];
    int tid = threadIdx.x, wave = tid >> 6, lane = tid & 63;
    int m0 = blockIdx.y * 128, n0 = blockIdx.x * 128;
    int wm0 = (wave >> 1) * 64, wn0 = (wave & 1) * 64;
    f32x4 acc[4][4];
    #pragma unroll
    for (int i = 0; i < 4; ++i)
        #pragma unroll
        for (int j = 0; j < 4; ++j) acc[i][j] = (f32x4){0.f, 0.f, 0.f, 0.f};

    int srow8 = lane >> 3;             // row within 8-row chunk
    int schunk = lane & 7;             // 16B chunk within 128B row
    for (int k0 = 0; k0 < K3; k0 += 64) {
        #pragma unroll
        for (int rep = 0; rep < 4; ++rep) {
            int ci = wave * 4 + rep;
            int row = ci * 8 + srow8;
            int sc = schunk ^ (row & 7);
            int gm = m0 + row; if (gm >= M) gm = M - 1;
            gload16(Asm + ci * 512 + lane * 8,
                    A3 + (size_t)gm * K3 + k0 + sc * 8);
            int gn = n0 + row; if (gn >= N) gn = N - 1;
            gload16(Bsm + ci * 512 + lane * 8,
                    B3 + (size_t)gn * K3 + k0 + sc * 8);
        }
        __syncthreads();
        #pragma unroll
        for (int ks = 0; ks < 2; ++ks) {
            bfrag a[4], b[4];
            #pragma unroll
            for (int i = 0; i < 4; ++i) {
                int ar = wm0 + i * 16 + (lane & 15);
                int ab = (ar * 128 + ks * 64 + (lane >> 4) * 16) ^ ((ar & 7) << 4);
                a[i] = *(const bfrag*)((const char*)Asm + ab);
                int br = wn0 + i * 16 + (lane & 15);
                int bb = (br * 128 + ks * 64 + (lane >> 4) * 16) ^ ((br & 7) << 4);
                b[i] = *(const bfrag*)((const char*)Bsm + bb);
            }
            #pragma unroll
            for (int i = 0; i < 4; ++i)
                #pragma unroll
                for (int j = 0; j < 4; ++j)
                    acc[i][j] = __builtin_amdgcn_mfma_f32_16x16x32_bf16(a[i], b[j], acc[i][j], 0, 0, 0);
        }
        __syncthreads();
    }
    #pragma unroll
    for (int i = 0; i < 4; ++i) {
        #pragma unroll
        for (int r = 0; r < 4; ++r) {
            int m = m0 + wm0 + i * 16 + ((lane >> 4) << 2) + r;
            if (m >= M) continue;
            #pragma unroll
            for (int j = 0; j < 4; ++j) {
                int n = n0 + wn0 + j * 16 + (lane & 15);
                if (n >= N) continue;
                float v = acc[i][j][r];
                if (bias) v += bias[n];
                size_t oi;
                if (outMode == 0) oi = (size_t)m * N + n;
                else { int bb2 = m & 127, tt = m >> 7; oi = ((size_t)bb2 * TT + tt) * (size_t)VV + n; }
                C[oi] = v;
            }
        }
    }
}

// ---------- fused LSTM step: gates = h3 @ whh3^T + xg[t] + gb ; update; emit h3(t+1) ----------
// grid (32 n-tiles, 2 m-tiles), 256 thr. BM=64, BN=64 (4 gates x 16 k), BK=128.
__global__ __launch_bounds__(256) void lstm_fused(
    int t, unsigned short* __restrict__ H3,
    const unsigned short* __restrict__ W3,
    const float* __restrict__ xg, const float* __restrict__ gbv,
    float* __restrict__ cbuf)
{
    __shared__ unsigned short Asm[64 * 128];
    __shared__ unsigned short Bsm[64 * 128];
    int tid = threadIdx.x, wave = tid >> 6, lane = tid & 63;
    int x = blockIdx.x;            // k-high tile: k = x*16 + (lane&15)
    int b0 = blockIdx.y * 64;
    const unsigned short* A3 = H3 + (size_t)t * 128 * 1536;
    unsigned short* Hout = H3 + (size_t)(t + 1) * 128 * 1536;
    f32x4 acc[4];
    #pragma unroll
    for (int j = 0; j < 4; ++j) acc[j] = (f32x4){0.f, 0.f, 0.f, 0.f};

    int srow4 = lane >> 4;          // row within 4-row chunk
    int schunk = lane & 15;         // 16B chunk within 256B row
    for (int k0 = 0; k0 < 1536; k0 += 128) {
        #pragma unroll
        for (int rep = 0; rep < 4; ++rep) {
            int ci = wave * 4 + rep;
            int row = ci * 4 + srow4;
            int sc = schunk ^ (row & 15);
            gload16(Asm + ci * 512 + lane * 8,
                    A3 + (size_t)(b0 + row) * 1536 + k0 + sc * 8);
            gload16(Bsm + ci * 512 + lane * 8,
                    W3 + (size_t)(x * 64 + row) * 1536 + k0 + sc * 8);
        }
        __syncthreads();
        #pragma unroll
        for (int ks = 0; ks < 4; ++ks) {
            int ar = wave * 16 + (lane & 15);
            int ab = (ar * 256 + ks * 64 + (lane >> 4) * 16) ^ ((ar & 15) << 4);
            bfrag af = *(const bfrag*)((const char*)Asm + ab);
            #pragma unroll
            for (int nf = 0; nf < 4; ++nf) {
                int br = nf * 16 + (lane & 15);
                int bbv = (br * 256 + ks * 64 + (lane >> 4) * 16) ^ ((br & 15) << 4);
                bfrag bf = *(const bfrag*)((const char*)Bsm + bbv);
                acc[nf] = __builtin_amdgcn_mfma_f32_16x16x32_bf16(af, bf, acc[nf], 0, 0, 0);
            }
        }
        __syncthreads();
    }
    int k = x * 16 + (lane & 15);
    #pragma unroll
    for (int r = 0; r < 4; ++r) {
        int b = b0 + wave * 16 + ((lane >> 4) << 2) + r;
        size_t xb = ((size_t)t * 128 + b) * 2048;
        size_t gbb = (size_t)b * 2048;
        float gi = acc[0][r] + xg[xb + k]        + gbv[gbb + k];
        float gf = acc[1][r] + xg[xb + 512 + k]  + gbv[gbb + 512 + k];
        float gg = acc[2][r] + xg[xb + 1024 + k] + gbv[gbb + 1024 + k];
        float go = acc[3][r] + xg[xb + 1536 + k] + gbv[gbb + 1536 + k];
        float si = 1.f / (1.f + expf(-gi));
        float sf = 1.f / (1.f + expf(-gf));
        float so = 1.f / (1.f + expf(-go));
        float tg = tanhf(gg);
        float cold = cbuf[(size_t)b * 512 + k];
        float cn = sf * cold + si * tg;
        float hn = so * tanhf(cn);
        cbuf[(size_t)b * 512 + k] = cn;
        unsigned short hi = f2bf(hn);
        unsigned short lo = f2bf(hn - bf2f(hi));
        unsigned short* hr = Hout + (size_t)b * 1536;
        hr[k] = hi; hr[512 + k] = hi; hr[1024 + k] = lo;
    }
}

// ---------- small helpers (unchanged from R1) ----------
__global__ __launch_bounds__(512) void matvec_col_partial(
    const float* __restrict__ W, int ldw, int koff,
    const float* __restrict__ vin, float* __restrict__ part)
{
    int k = threadIdx.x;
    int o0 = blockIdx.x * 16;
    float acc = 0.f;
    #pragma unroll
    for (int o = 0; o < 16; ++o)
        acc += W[(size_t)(o0 + o) * ldw + koff + k] * vin[o0 + o];
    part[blockIdx.x * 512 + k] = acc;
}

__global__ __launch_bounds__(512) void matvec_combine(
    const float* __restrict__ part, float* __restrict__ vout)
{
    int k = threadIdx.x;
    float s = 0.f;
    #pragma unroll
    for (int c = 0; c < 32; ++c) s += part[c * 512 + k];
    vout[k] = s;
}

__global__ __launch_bounds__(256) void attn_ctx(
    const float* __restrict__ enc, const float* __restrict__ u,
    float* __restrict__ ctx)
{
    __shared__ float su[HH];
    __shared__ float sw[SS];
    __shared__ float ssum;
    int b = blockIdx.x, tid = threadIdx.x;
    su[tid] = u[tid];
    su[tid + 256] = u[tid + 256];
    __syncthreads();
    const float* eb = enc + (size_t)b * SS * HH;
    int wave = tid >> 6, lane = tid & 63;
    for (int s = wave; s < SS; s += 4) {
        const float* row = eb + s * HH;
        float acc = 0.f;
        for (int k = lane; k < HH; k += 64) acc += row[k] * su[k];
        #pragma unroll
        for (int off = 32; off; off >>= 1) acc += __shfl_down(acc, off);
        if (lane == 0) sw[s] = acc;
    }
    __syncthreads();
    if (tid == 0) {
        float mx = sw[0];
        for (int s = 1; s < SS; ++s) mx = fmaxf(mx, sw[s]);
        float sum = 0.f;
        for (int s = 0; s < SS; ++s) { float e = expf(sw[s] - mx); sw[s] = e; sum += e; }
        ssum = sum;
    }
    __syncthreads();
    float inv = 1.0f / ssum;
    for (int k = tid; k < HH; k += 256) {
        float acc = 0.f;
        #pragma unroll 4
        for (int s = 0; s < SS; ++s) acc += sw[s] * eb[s * HH + k];
        ctx[(size_t)b * HH + k] = acc * inv;
    }
}

// old fp32 vector GEMM, kept only for gbase (ctx @ Wc^T + b_ih + b_hh)
__global__ __launch_bounds__(256) void gemm_nt(
    int M, int N, int K,
    const float* __restrict__ A, int lda,
    const float* __restrict__ Bm, int ldb, int kob,
    const float* __restrict__ bias1, const float* __restrict__ bias2,
    float* __restrict__ C)
{
    __shared__ float As[16][132];
    __shared__ float Bs[16][132];
    int tid = threadIdx.x;
    int m0 = blockIdx.y * 128, n0 = blockIdx.x * 128;
    int tn = tid & 15, tm = tid >> 4;
    float acc[8][8];
    #pragma unroll
    for (int i = 0; i < 8; ++i)
        #pragma unroll
        for (int j = 0; j < 8; ++j) acc[i][j] = 0.f;
    int lr = tid >> 2;
    int lk = (tid & 3) * 4;
    for (int k0 = 0; k0 < K; k0 += 16) {
        #pragma unroll
        for (int half = 0; half < 2; ++half) {
            int mr = lr + half * 64;
            int m = m0 + mr;
            float4 va = make_float4(0.f, 0.f, 0.f, 0.f);
            if (m < M) va = *(const float4*)(A + (size_t)m * lda + k0 + lk);
            As[lk + 0][mr] = va.x; As[lk + 1][mr] = va.y;
            As[lk + 2][mr] = va.z; As[lk + 3][mr] = va.w;
            int n = n0 + mr;
            float4 vb = make_float4(0.f, 0.f, 0.f, 0.f);
            if (n < N) vb = *(const float4*)(Bm + (size_t)n * ldb + kob + k0 + lk);
            Bs[lk + 0][mr] = vb.x; Bs[lk + 1][mr] = vb.y;
            Bs[lk + 2][mr] = vb.z; Bs[lk + 3][mr] = vb.w;
        }
        __syncthreads();
        #pragma unroll
        for (int kk = 0; kk < 16; ++kk) {
            float4 a0 = *(const float4*)&As[kk][tm * 8];
            float4 a1 = *(const float4*)&As[kk][tm * 8 + 4];
            float4 b0 = *(const float4*)&Bs[kk][tn * 8];
            float4 b1 = *(const float4*)&Bs[kk][tn * 8 + 4];
            float av[8] = {a0.x, a0.y, a0.z, a0.w, a1.x, a1.y, a1.z, a1.w};
            float bv[8] = {b0.x, b0.y, b0.z, b0.w, b1.x, b1.y, b1.z, b1.w};
            #pragma unroll
            for (int i = 0; i < 8; ++i)
                #pragma unroll
                for (int j = 0; j < 8; ++j)
                    acc[i][j] += av[i] * bv[j];
        }
        __syncthreads();
    }
    #pragma unroll
    for (int i = 0; i < 8; ++i) {
        int m = m0 + tm * 8 + i;
        if (m >= M) continue;
        #pragma unroll
        for (int j = 0; j < 8; ++j) {
            int n = n0 + tn * 8 + j;
            if (n >= N) continue;
            float v = acc[i][j];
            if (bias1) v += bias1[n];
            if (bias2) v += bias2[n];
            C[(size_t)m * N + n] = v;
        }
    }
}

__global__ __launch_bounds__(256) void zero_c(float* __restrict__ c)
{
    int i = blockIdx.x * 256 + threadIdx.x;
    c[i] = 0.f;
}

__global__ __launch_bounds__(256) void argmax_k(
    const float* __restrict__ logits, float* __restrict__ preds)
{
    int r = blockIdx.x * 4 + (threadIdx.x >> 6);
    int lane = threadIdx.x & 63;
    const float* row = logits + (size_t)r * VV;
    float best = -INFINITY;
    int bi = 0;
    for (int v = lane; v < VV; v += 64) {
        float x = row[v];
        if (x > best) { best = x; bi = v; }
    }
    #pragma unroll
    for (int off = 32; off; off >>= 1) {
        float ob = __shfl_down(best, off);
        int oi = __shfl_down(bi, off);
        if (ob > best || (ob == best && oi < bi)) { best = ob; bi = oi; }
    }
    if (lane == 0) preds[r] = (float)bi;
}

extern "C" void kernel_launch(void* const* d_in, const int* in_sizes, int n_in,
                              void* d_out, int out_size, void* d_ws, size_t ws_size,
                              hipStream_t stream) {
    const float* ehs   = (const float*)d_in[0];
    const float* enc   = (const float*)d_in[1];
    const int*   tgt   = (const int*)d_in[2];
    const float* emb   = (const float*)d_in[4];
    const float* fc1w  = (const float*)d_in[5];
    const float* fc2w  = (const float*)d_in[7];
    const float* fc3w  = (const float*)d_in[9];
    const float* fc4w  = (const float*)d_in[11];
    const float* attnw = (const float*)d_in[13];
    const float* wih   = (const float*)d_in[14];
    const float* whh   = (const float*)d_in[15];
    const float* bih   = (const float*)d_in[16];
    const float* bhh   = (const float*)d_in[17];
    const float* outw  = (const float*)d_in[18];
    const float* outb  = (const float*)d_in[19];
    float* out = (float*)d_out;
    float* ws  = (float*)d_ws;

    float* vA   = ws + OFF_VA;
    float* vB   = ws + OFF_VB;
    float* u    = ws + OFF_U;
    float* part = ws + OFF_PART;
    float* ctx  = ws + OFF_CTX;
    float* gb   = ws + OFF_GB;
    float* xg   = ws + OFF_XG;
    float* cb   = ws + OFF_C;
    unsigned short* bfb = (unsigned short*)(ws + FP32_WS_FLOATS);
    unsigned short* H3   = bfb + O_H3;
    unsigned short* WHH3 = bfb + O_WHH3;
    unsigned short* A3X  = bfb + O_A3X;
    unsigned short* B3X  = bfb + O_B3X;
    unsigned short* B3L  = bfb + O_B3L;

    // u = W1e^T W2^T W3^T W4^T attn_w  (softmax shift-invariance kills h & bias terms)
    matvec_col_partial<<<32, 512, 0, stream>>>(fc4w, 512, 0, attnw, part);
    matvec_combine<<<1, 512, 0, stream>>>(part, vA);
    matvec_col_partial<<<32, 512, 0, stream>>>(fc3w, 512, 0, vA, part);
    matvec_combine<<<1, 512, 0, stream>>>(part, vB);
    matvec_col_partial<<<32, 512, 0, stream>>>(fc2w, 512, 0, vB, part);
    matvec_combine<<<1, 512, 0, stream>>>(part, vA);
    matvec_col_partial<<<32, 512, 0, stream>>>(fc1w, 1024, 0, vA, part);
    matvec_combine<<<1, 512, 0, stream>>>(part, u);

    attn_ctx<<<128, 256, 0, stream>>>(enc, u, ctx);

    // gbase = ctx @ Wc^T + b_ih + b_hh  (fp32 path, tiny)
    {
        dim3 g(16, 1);
        gemm_nt<<<g, 256, 0, stream>>>(128, 2048, 512, ctx, 512,
                                       wih, 1536, 1024, bih, bhh, gb);
    }

    // xg = gather(emb, tgt) @ Wx^T  via split-bf16 MFMA
    conv_split<<<2048, 256, 0, stream>>>(wih, 1536, 0, 1024, 0, 1, nullptr, B3X);
    conv_split<<<3456, 256, 0, stream>>>(emb, 1024, 0, 1024, 1, 0, tgt, A3X);
    {
        dim3 g(16, 27);
        gemm_bf16_nt<<<g, 256, 0, stream>>>(3456, 2048, 3072, A3X, B3X,
                                            nullptr, xg, 0);
    }

    // B3L overlays A3X/B3X — only after the xg gemm
    conv_split<<<8000, 256, 0, stream>>>(outw, 512, 0, 512, 0, 1, nullptr, B3L);
    conv_split<<<2048, 256, 0, stream>>>(whh, 512, 0, 512, 2, 1, nullptr, WHH3);
    conv_split<<<128, 256, 0, stream>>>(ehs, 512, 0, 512, 0, 0, nullptr, H3);
    zero_c<<<256, 256, 0, stream>>>(cb);

    for (int t = 0; t < TT; ++t) {
        dim3 g(32, 2);
        lstm_fused<<<g, 256, 0, stream>>>(t, H3, WHH3, xg, gb, cb);
    }

    // logits = H3[1:] @ B3L^T + out_b, scattered to (b, t, v)
    {
        dim3 g(63, 27);
        gemm_bf16_nt<<<g, 256, 0, stream>>>(3456, 8000, 1536,
                                            H3 + (size_t)128 * 1536, B3L,
                                            outb, out, 1);
    }

    argmax_k<<<864, 256, 0, stream>>>(out, out + (size_t)TT * 128 * VV);
}